// Round 1
// baseline (581.113 us; speedup 1.0000x reference)
//
#include <hip/hip_runtime.h>
#include <hip/hip_bf16.h>
#include <stdint.h>

#define BB 512
#define HH 1024
#define NN 16384
#define MM 128
#define RR 4

typedef short short8 __attribute__((ext_vector_type(8)));
typedef float floatx4 __attribute__((ext_vector_type(4)));

__device__ __forceinline__ unsigned short f2bf(float f) {
  unsigned int u = __float_as_uint(f);
  unsigned int r = (u + 0x7fffu + ((u >> 16) & 1u)) >> 16;
  return (unsigned short)r;
}

__device__ __forceinline__ floatx4 mfma16(short8 a, short8 b, floatx4 c) {
  return __builtin_amdgcn_mfma_f32_16x16x32_bf16(a, b, c, 0, 0, 0);
}

// ---------------- K1: fused controller projection GEMM ----------------
// raw[b][r] = sum_k h[b][k] * W[r][k], rows: 0-127 key, 128-255 erase,
// 256-383 add, 384 beta, 385 gate, 386-388 shift. split-K (z=2) via atomics.
__global__ __launch_bounds__(256) void k1_proj(
    const float* __restrict__ h, const float* __restrict__ key_w,
    const float* __restrict__ erase_w, const float* __restrict__ add_w,
    const float* __restrict__ beta_w, const float* __restrict__ gate_w,
    const float* __restrict__ shift_w, float* __restrict__ raw) {
  __shared__ float hsT[32][34];
  __shared__ float wsT[32][34];
  const int t = threadIdx.x;
  const int b0 = blockIdx.x * 32;
  const int r0 = blockIdx.y * 32;
  const int kb = blockIdx.z * 512;
  const int tb = t & 15, tr = t >> 4;
  float acc00 = 0.f, acc01 = 0.f, acc10 = 0.f, acc11 = 0.f;
  for (int ko = 0; ko < 16; ++ko) {
    int kc = kb + ko * 32;
    __syncthreads();
    #pragma unroll
    for (int p = 0; p < 4; ++p) {
      int idx = t + p * 256;
      int col = idx & 31, row = idx >> 5;
      hsT[col][row] = h[(b0 + row) * HH + kc + col];
      int rg = r0 + row;
      float wv = 0.f;
      if (rg < 128)       wv = key_w[rg * HH + kc + col];
      else if (rg < 256)  wv = erase_w[(rg - 128) * HH + kc + col];
      else if (rg < 384)  wv = add_w[(rg - 256) * HH + kc + col];
      else if (rg == 384) wv = beta_w[kc + col];
      else if (rg == 385) wv = gate_w[kc + col];
      else if (rg < 389)  wv = shift_w[(rg - 386) * HH + kc + col];
      wsT[col][row] = wv;
    }
    __syncthreads();
    #pragma unroll
    for (int kk = 0; kk < 32; ++kk) {
      float a0 = hsT[kk][2 * tb], a1 = hsT[kk][2 * tb + 1];
      float w0 = wsT[kk][2 * tr], w1 = wsT[kk][2 * tr + 1];
      acc00 += a0 * w0; acc01 += a0 * w1;
      acc10 += a1 * w0; acc11 += a1 * w1;
    }
  }
  int bA = b0 + 2 * tb, bB = bA + 1;
  int rA = r0 + 2 * tr, rB = rA + 1;
  if (rA < 389) {
    unsafeAtomicAdd(&raw[bA * 392 + rA], acc00);
    unsafeAtomicAdd(&raw[bB * 392 + rA], acc10);
  }
  if (rB < 389) {
    unsafeAtomicAdd(&raw[bA * 392 + rB], acc01);
    unsafeAtomicAdd(&raw[bB * 392 + rB], acc11);
  }
}

// ---------------- K2: bias + activations + k-norm + s-softmax ----------------
__global__ __launch_bounds__(128) void k2_final(
    const float* __restrict__ raw, const float* __restrict__ key_b,
    const float* __restrict__ erase_b, const float* __restrict__ add_b,
    const float* __restrict__ beta_b, const float* __restrict__ gate_b,
    const float* __restrict__ shift_b, float* __restrict__ kt,
    unsigned short* __restrict__ kbf, unsigned short* __restrict__ ebfT,
    unsigned short* __restrict__ abfT, float* __restrict__ beta,
    float* __restrict__ g, float* __restrict__ s3, float* __restrict__ knorm) {
  __shared__ float red[128];
  const int b = blockIdx.x, t = threadIdx.x;
  const float* rb = raw + b * 392;
  float kv = fminf(fmaxf(rb[t] + key_b[t], 0.f), 1.f);
  kt[b * MM + t] = kv;
  kbf[b * MM + t] = f2bf(kv);
  float ev = fminf(fmaxf(rb[128 + t] + erase_b[t], 0.f), 1.f);
  ebfT[t * BB + b] = f2bf(ev);
  float av = fminf(fmaxf(rb[256 + t] + add_b[t], 0.f), 1.f);
  abfT[t * BB + b] = f2bf(av);
  red[t] = kv * kv;
  __syncthreads();
  for (int off = 64; off >= 1; off >>= 1) {
    if (t < off) red[t] += red[t + off];
    __syncthreads();
  }
  if (t == 0) {
    knorm[b] = sqrtf(red[0]);
    beta[b] = fmaxf(rb[384] + beta_b[0], 0.f);
    g[b] = fminf(fmaxf(rb[385] + gate_b[0], 0.f), 1.f);
    float x0 = rb[386] + shift_b[0];
    float x1 = rb[387] + shift_b[1];
    float x2 = rb[388] + shift_b[2];
    float mx = fmaxf(x0, fmaxf(x1, x2));
    float e0 = __expf(x0 - mx), e1 = __expf(x1 - mx), e2 = __expf(x2 - mx);
    float inv = 1.f / (e0 + e1 + e2);
    s3[b * 3 + 0] = e0 * inv; s3[b * 3 + 1] = e1 * inv; s3[b * 3 + 2] = e2 * inv;
  }
}

// ---------------- K3: m row norms + m_bf16 + m_bf16^T ----------------
__global__ __launch_bounds__(256) void k3_mprep(
    const float* __restrict__ m, unsigned short* __restrict__ mbf,
    unsigned short* __restrict__ mbfT, float* __restrict__ mnorm) {
  __shared__ float ldsT[128][65];
  const int t = threadIdx.x;
  const int n0 = blockIdx.x * 64;
  const int lane = t & 63, w = t >> 6;
  for (int ri = 0; ri < 16; ++ri) {
    int n = n0 + w * 16 + ri;
    float v0 = m[n * MM + lane];
    float v1 = m[n * MM + lane + 64];
    mbf[n * MM + lane] = f2bf(v0);
    mbf[n * MM + lane + 64] = f2bf(v1);
    float sq = v0 * v0 + v1 * v1;
    #pragma unroll
    for (int off = 32; off >= 1; off >>= 1) sq += __shfl_xor(sq, off, 64);
    if (lane == 0) mnorm[n] = sqrtf(sq);
  }
  for (int p = 0; p < 32; ++p) {
    int nloc = p * 2 + (t >> 7);
    int mc = t & 127;
    ldsT[mc][nloc] = m[(n0 + nloc) * MM + mc];
  }
  __syncthreads();
  for (int q = 0; q < 32; ++q) {
    int mc = q * 4 + (t >> 6);
    int nloc = t & 63;
    mbfT[mc * NN + n0 + nloc] = f2bf(ldsT[mc][nloc]);
  }
}

// ---------------- K4: sim = cos-sim GEMM (bf16 MFMA, K=128) ----------------
__global__ __launch_bounds__(256) void k4_sim(
    const unsigned short* __restrict__ kbf, const unsigned short* __restrict__ mbf,
    const float* __restrict__ knorm, const float* __restrict__ mnorm,
    float* __restrict__ sim) {
  const int t = threadIdx.x;
  const int lane = t & 63, w = t >> 6;
  const int n0 = blockIdx.x * 64;
  const int b0 = blockIdx.y * 64 + w * 16;
  const int lm = lane & 15, quad = lane >> 4;
  floatx4 acc[4];
  #pragma unroll
  for (int i = 0; i < 4; ++i) acc[i] = (floatx4){0.f, 0.f, 0.f, 0.f};
  #pragma unroll
  for (int s = 0; s < 4; ++s) {
    short8 avf = *(const short8*)(kbf + (b0 + lm) * MM + s * 32 + quad * 8);
    #pragma unroll
    for (int nt = 0; nt < 4; ++nt) {
      short8 bvf = *(const short8*)(mbf + (n0 + nt * 16 + lm) * MM + s * 32 + quad * 8);
      acc[nt] = mfma16(avf, bvf, acc[nt]);
    }
  }
  #pragma unroll
  for (int nt = 0; nt < 4; ++nt) {
    int n = n0 + nt * 16 + lm;
    float mn = mnorm[n];
    #pragma unroll
    for (int r = 0; r < 4; ++r) {
      int b = b0 + quad * 4 + r;
      float val = acc[nt][r] / (knorm[b] * mn + 1e-6f);
      sim[(size_t)b * NN + n] = val;
    }
  }
}

// ---------------- K5: per-row softmax stats (max, sum exp) ----------------
__global__ __launch_bounds__(1024) void k5_stats(
    const float* __restrict__ sim, const float* __restrict__ beta,
    float* __restrict__ rowmax, float* __restrict__ rowsum) {
  __shared__ float lmax[16];
  __shared__ float lsum[16];
  __shared__ float bmax;
  const int b = blockIdx.x, t = threadIdx.x;
  const int wid = t >> 6, lane = t & 63;
  float v[16];
  #pragma unroll
  for (int i = 0; i < 16; ++i) v[i] = sim[(size_t)b * NN + t + i * 1024];
  float mx = v[0];
  #pragma unroll
  for (int i = 1; i < 16; ++i) mx = fmaxf(mx, v[i]);
  #pragma unroll
  for (int off = 32; off >= 1; off >>= 1) mx = fmaxf(mx, __shfl_xor(mx, off, 64));
  if (lane == 0) lmax[wid] = mx;
  __syncthreads();
  if (t == 0) {
    float m2 = lmax[0];
    for (int i = 1; i < 16; ++i) m2 = fmaxf(m2, lmax[i]);
    bmax = m2;
  }
  __syncthreads();
  float gm = bmax;
  float bt = beta[b];
  float sum = 0.f;
  #pragma unroll
  for (int i = 0; i < 16; ++i) sum += __expf(bt * (v[i] - gm));
  #pragma unroll
  for (int off = 32; off >= 1; off >>= 1) sum += __shfl_xor(sum, off, 64);
  if (lane == 0) lsum[wid] = sum;
  __syncthreads();
  if (t == 0) {
    float s = 0.f;
    for (int i = 0; i < 16; ++i) s += lsum[i];
    rowsum[b] = s;
    rowmax[b] = gm;
  }
}

// ---------------- KT: ww (B,N) -> ww^T bf16 (N,B) ----------------
__global__ __launch_bounds__(256) void kt_wwT(
    const float* __restrict__ ww, unsigned short* __restrict__ wwT) {
  __shared__ float lds[64][65];
  const int t = threadIdx.x;
  const int n0 = blockIdx.x * 64, b0 = blockIdx.y * 64;
  const int c = t & 63, r = t >> 6;
  #pragma unroll
  for (int p = 0; p < 16; ++p)
    lds[r + 4 * p][c] = ww[(size_t)(b0 + r + 4 * p) * NN + n0 + c];
  __syncthreads();
  #pragma unroll
  for (int q = 0; q < 16; ++q) {
    int nr = r + 4 * q;
    wwT[(size_t)(n0 + nr) * BB + b0 + c] = f2bf(lds[c][nr]);
  }
}

// ---------------- KC: fused gate + 3-tap circular conv for 5 heads ----------------
__global__ __launch_bounds__(256) void kc_update(
    const float* __restrict__ sim, const float* __restrict__ ww,
    const float* __restrict__ wr, const float* __restrict__ beta,
    const float* __restrict__ gv, const float* __restrict__ s3,
    const float* __restrict__ rowmax, const float* __restrict__ rowsum,
    float* __restrict__ out_ww, float* __restrict__ out_wr) {
  __shared__ float wg[5][264];
  const int b = blockIdx.x, t = threadIdx.x;
  const int chunk0 = blockIdx.y * 2048;
  const float bt = beta[b], g = gv[b];
  const float mx = rowmax[b], invZ = 1.f / rowsum[b];
  const float s0 = s3[b * 3], s1 = s3[b * 3 + 1], s2 = s3[b * 3 + 2];
  const float om = 1.f - g;
  const float* pv[5];
  float* po[5];
  pv[0] = ww + (size_t)b * NN;
  po[0] = out_ww + (size_t)b * NN;
  #pragma unroll
  for (int h = 1; h < 5; ++h) {
    pv[h] = wr + ((size_t)(h - 1) * BB + b) * NN;
    po[h] = out_wr + ((size_t)(h - 1) * BB + b) * NN;
  }
  for (int it = 0; it < 8; ++it) {
    int nbase = chunk0 + it * 256;
    int n = nbase + t;
    float sv = sim[(size_t)b * NN + n];
    float wcv = __expf(bt * (sv - mx)) * invZ;
    #pragma unroll
    for (int h = 0; h < 5; ++h) wg[h][t + 1] = g * wcv + om * pv[h][n];
    if (t < 2) {
      int hn = (t == 0) ? ((nbase - 1) & (NN - 1)) : ((nbase + 256) & (NN - 1));
      int li = (t == 0) ? 0 : 257;
      float sh = sim[(size_t)b * NN + hn];
      float wch = __expf(bt * (sh - mx)) * invZ;
      #pragma unroll
      for (int h = 0; h < 5; ++h) wg[h][li] = g * wch + om * pv[h][hn];
    }
    __syncthreads();
    #pragma unroll
    for (int h = 0; h < 5; ++h) {
      float wt = s0 * wg[h][t + 2] + s1 * wg[h][t + 1] + s2 * wg[h][t];
      po[h][n] = wt;
    }
    __syncthreads();
  }
}

// ---------------- KD: m_t = m*(1 - ww^T e) + ww^T a (bf16 MFMA, K=512) ----------------
__global__ __launch_bounds__(256) void kd_mem(
    const unsigned short* __restrict__ wwT, const unsigned short* __restrict__ ebfT,
    const unsigned short* __restrict__ abfT, const float* __restrict__ m,
    float* __restrict__ out_m) {
  const int t = threadIdx.x;
  const int lane = t & 63, w = t >> 6;
  const int lm = lane & 15, quad = lane >> 4;
  const int nb = blockIdx.x * 64 + w * 16;
  floatx4 accE[8], accA[8];
  #pragma unroll
  for (int i = 0; i < 8; ++i) {
    accE[i] = (floatx4){0.f, 0.f, 0.f, 0.f};
    accA[i] = (floatx4){0.f, 0.f, 0.f, 0.f};
  }
  for (int s = 0; s < 16; ++s) {
    short8 av = *(const short8*)(wwT + (size_t)(nb + lm) * BB + s * 32 + quad * 8);
    #pragma unroll
    for (int mt = 0; mt < 8; ++mt) {
      short8 evf = *(const short8*)(ebfT + (mt * 16 + lm) * BB + s * 32 + quad * 8);
      short8 avf = *(const short8*)(abfT + (mt * 16 + lm) * BB + s * 32 + quad * 8);
      accE[mt] = mfma16(av, evf, accE[mt]);
      accA[mt] = mfma16(av, avf, accA[mt]);
    }
  }
  #pragma unroll
  for (int mt = 0; mt < 8; ++mt) {
    int mc = mt * 16 + lm;
    #pragma unroll
    for (int r = 0; r < 4; ++r) {
      int n = nb + quad * 4 + r;
      float mv = m[n * MM + mc];
      out_m[n * MM + mc] = mv * (1.f - accE[mt][r]) + accA[mt][r];
    }
  }
}

// ---------------- KE: r_t = einsum(wr, m) (bf16 MFMA, split-K=16 + atomics) ----------------
__global__ __launch_bounds__(256) void ke_read(
    const float* __restrict__ wr, const unsigned short* __restrict__ mbfT,
    float* __restrict__ out_r) {
  const int t = threadIdx.x;
  const int lane = t & 63, w = t >> 6;
  const int lm = lane & 15, quad = lane >> 4;
  const int rb0 = blockIdx.x * 64 + w * 16;
  const int kc0 = blockIdx.y * 1024;
  floatx4 acc[8];
  #pragma unroll
  for (int i = 0; i < 8; ++i) acc[i] = (floatx4){0.f, 0.f, 0.f, 0.f};
  for (int s = 0; s < 32; ++s) {
    int ns = kc0 + s * 32 + quad * 8;
    const float* ap = wr + (size_t)(rb0 + lm) * NN + ns;
    floatx4 f0 = *(const floatx4*)(ap);
    floatx4 f1 = *(const floatx4*)(ap + 4);
    short8 av;
    av[0] = (short)f2bf(f0[0]); av[1] = (short)f2bf(f0[1]);
    av[2] = (short)f2bf(f0[2]); av[3] = (short)f2bf(f0[3]);
    av[4] = (short)f2bf(f1[0]); av[5] = (short)f2bf(f1[1]);
    av[6] = (short)f2bf(f1[2]); av[7] = (short)f2bf(f1[3]);
    #pragma unroll
    for (int mt = 0; mt < 8; ++mt) {
      short8 bv = *(const short8*)(mbfT + (size_t)(mt * 16 + lm) * NN + ns);
      acc[mt] = mfma16(av, bv, acc[mt]);
    }
  }
  #pragma unroll
  for (int mt = 0; mt < 8; ++mt) {
    int mc = mt * 16 + lm;
    #pragma unroll
    for (int r = 0; r < 4; ++r) {
      int rb = rb0 + quad * 4 + r;
      int rr = rb >> 9, bb = rb & 511;
      unsafeAtomicAdd(&out_r[bb * (RR * MM) + rr * MM + mc], acc[mt][r]);
    }
  }
}

extern "C" void kernel_launch(void* const* d_in, const int* in_sizes, int n_in,
                              void* d_out, int out_size, void* d_ws, size_t ws_size,
                              hipStream_t stream) {
  const float* h_t    = (const float*)d_in[0];
  const float* wr     = (const float*)d_in[1];
  const float* ww     = (const float*)d_in[2];
  const float* m      = (const float*)d_in[3];
  const float* key_w  = (const float*)d_in[4];
  const float* key_b  = (const float*)d_in[5];
  const float* beta_w = (const float*)d_in[6];
  const float* beta_b = (const float*)d_in[7];
  const float* gate_w = (const float*)d_in[8];
  const float* gate_b = (const float*)d_in[9];
  const float* shift_w = (const float*)d_in[10];
  const float* shift_b = (const float*)d_in[11];
  const float* erase_w = (const float*)d_in[14];
  const float* erase_b = (const float*)d_in[15];
  const float* add_w   = (const float*)d_in[16];
  const float* add_b   = (const float*)d_in[17];

  char* wsb = (char*)d_ws;
  float* raw            = (float*)(wsb + 0);          // 512*392*4 = 802816
  float* kt             = (float*)(wsb + 802816);     // 262144
  unsigned short* kbf   = (unsigned short*)(wsb + 1064960);  // 131072
  unsigned short* ebfT  = (unsigned short*)(wsb + 1196032);  // 131072
  unsigned short* abfT  = (unsigned short*)(wsb + 1327104);  // 131072
  float* beta           = (float*)(wsb + 1458176);    // 2048
  float* g              = (float*)(wsb + 1460224);    // 2048
  float* s3             = (float*)(wsb + 1462272);    // 6144
  float* knorm          = (float*)(wsb + 1468416);    // 2048
  float* rowmax         = (float*)(wsb + 1470464);    // 2048
  float* rowsum         = (float*)(wsb + 1472512);    // 2048
  float* mnorm          = (float*)(wsb + 1474560);    // 65536
  unsigned short* mbf   = (unsigned short*)(wsb + 1540096);  // 4194304
  unsigned short* mbfT  = (unsigned short*)(wsb + 5734400);  // 4194304
  unsigned short* wwT   = (unsigned short*)(wsb + 9928704);  // 16777216
  float* sim            = (float*)(wsb + 26705920);   // 33554432  (total ~57.5 MB)

  float* out_r  = (float*)d_out;                 // (B,R,M)  262144
  float* out_wr = (float*)d_out + 262144;        // (R,B,N)  33554432
  float* out_ww = (float*)d_out + 33816576;      // (B,N)    8388608
  float* out_m  = (float*)d_out + 42205184;      // (N,M)    2097152

  hipMemsetAsync(d_out, 0, 262144 * sizeof(float), stream);   // r_t accum
  hipMemsetAsync(raw, 0, 802816, stream);                     // split-K accum

  k1_proj<<<dim3(16, 13, 2), 256, 0, stream>>>(h_t, key_w, erase_w, add_w,
                                               beta_w, gate_w, shift_w, raw);
  k2_final<<<512, 128, 0, stream>>>(raw, key_b, erase_b, add_b, beta_b, gate_b,
                                    shift_b, kt, kbf, ebfT, abfT, beta, g, s3, knorm);
  k3_mprep<<<256, 256, 0, stream>>>(m, mbf, mbfT, mnorm);
  k4_sim<<<dim3(256, 8), 256, 0, stream>>>(kbf, mbf, knorm, mnorm, sim);
  k5_stats<<<512, 1024, 0, stream>>>(sim, beta, rowmax, rowsum);
  kt_wwT<<<dim3(256, 8), 256, 0, stream>>>(ww, wwT);
  kc_update<<<dim3(512, 8), 256, 0, stream>>>(sim, ww, wr, beta, g, s3,
                                              rowmax, rowsum, out_ww, out_wr);
  kd_mem<<<256, 256, 0, stream>>>(wwT, ebfT, abfT, m, out_m);
  ke_read<<<dim3(32, 16), 256, 0, stream>>>(wr, mbfT, out_r);
}